// Round 1
// baseline (691.451 us; speedup 1.0000x reference)
//
#include <hip/hip_runtime.h>
#include <math.h>

#define HH 2048
#define WW 2048
#define NB 256

// softmax-expectation accumulator tuple: running max, sum(e), sum(e*x), sum(e*y)
struct Tup { float m, z, sx, sy; };

__device__ __forceinline__ void comb(Tup& a, const Tup& b) {
  float Mn = fmaxf(a.m, b.m);
  // (m==Mn)?1:expf guard avoids (-inf) - (-inf) = NaN when merging two identities
  float w1 = (a.m == Mn) ? 1.0f : expf(a.m - Mn);
  float w2 = (b.m == Mn) ? 1.0f : expf(b.m - Mn);
  a.z  = a.z  * w1 + b.z  * w2;
  a.sx = a.sx * w1 + b.sx * w2;
  a.sy = a.sy * w1 + b.sy * w2;
  a.m  = Mn;
}

// Online-softmax reduce of one row (WW columns). Result (m, z, sx) valid in thread 0.
__device__ Tup row_reduce(const float* __restrict__ rowp) {
  const int tid = threadIdx.x;
  const float4* r4 = (const float4*)rowp;
  float m = -INFINITY, z = 0.0f, sx = 0.0f;
#pragma unroll
  for (int p = 0; p < WW / (4 * NB); ++p) {
    int i4 = tid + NB * p;
    float4 v = r4[i4];
    float vv[4] = {v.x, v.y, v.z, v.w};
    float c0 = (float)(i4 * 4);
#pragma unroll
    for (int k = 0; k < 4; ++k) {
      float x = vv[k] * 100.0f;   // BETA, matches reference f32 multiply
      if (x > m) {
        float sc = expf(m - x);   // first iter: expf(-inf) = 0
        z  = z  * sc + 1.0f;
        sx = sx * sc + (c0 + (float)k);
        m = x;
      } else {
        float w = expf(x - m);
        z  += w;
        sx += w * (c0 + (float)k);
      }
    }
  }
  __shared__ float sm_[NB], sz_[NB], ss_[NB];
  sm_[tid] = m; sz_[tid] = z; ss_[tid] = sx;
  __syncthreads();
  for (int off = NB / 2; off > 0; off >>= 1) {
    if (tid < off) {
      Tup a = {sm_[tid], sz_[tid], ss_[tid], 0.0f};
      Tup b = {sm_[tid + off], sz_[tid + off], ss_[tid + off], 0.0f};
      comb(a, b);
      sm_[tid] = a.m; sz_[tid] = a.z; ss_[tid] = a.sx;
    }
    __syncthreads();
  }
  Tup t = {sm_[0], sz_[0], ss_[0], 0.0f};
  return t;
}

__device__ Tup block_reduce4(Tup t) {
  __shared__ float am[NB], az[NB], axx[NB], ayy[NB];
  const int tid = threadIdx.x;
  __syncthreads();
  am[tid] = t.m; az[tid] = t.z; axx[tid] = t.sx; ayy[tid] = t.sy;
  __syncthreads();
  for (int off = NB / 2; off > 0; off >>= 1) {
    if (tid < off) {
      Tup a = {am[tid], az[tid], axx[tid], ayy[tid]};
      Tup b = {am[tid + off], az[tid + off], axx[tid + off], ayy[tid + off]};
      comb(a, b);
      am[tid] = a.m; az[tid] = a.z; axx[tid] = a.sx; ayy[tid] = a.sy;
    }
    __syncthreads();
  }
  Tup r = {am[0], az[0], axx[0], ayy[0]};
  return r;
}

// ws layout (floats): [0..15] int counters, [16..47] state, [48..] float4 partials
// state: [0..21] out(11x2), [22] dis, [23] dis_sum, [24] dis_num

__global__ __launch_bounds__(NB) void k_full(const float* __restrict__ heat, float* ws) {
  int* counters = (int*)ws;
  float* state = ws + 16;
  float4* partials = (float4*)(ws + 48);
  const int b = blockIdx.x;
  const int ch = 9 + (b >> 11);
  const int r = b & (HH - 1);
  const float* rowp = heat + ((size_t)ch * HH + r) * WW;
  Tup t = row_reduce(rowp);
  __shared__ int s_last;
  if (threadIdx.x == 0) {
    partials[b] = make_float4(t.m, t.z, t.sx, 0.0f);
    __threadfence();
    int old = atomicAdd(&counters[0], 1);
    s_last = (old == 2 * HH - 1) ? 1 : 0;
  }
  __syncthreads();
  if (!s_last) return;
  __threadfence();
  float res[2][2];
  for (int c = 0; c < 2; ++c) {
    Tup acc = {-INFINITY, 0.0f, 0.0f, 0.0f};
    for (int rr = threadIdx.x; rr < HH; rr += NB) {
      float4 p = partials[c * HH + rr];
      Tup q = {p.x, p.y, p.z, p.y * (float)rr};  // sy = z_row * row
      comb(acc, q);
    }
    acc = block_reduce4(acc);
    if (threadIdx.x == 0) { res[c][0] = acc.sx / acc.z; res[c][1] = acc.sy / acc.z; }
  }
  if (threadIdx.x == 0) {
    state[18] = res[0][0]; state[19] = res[0][1];   // out[9]
    state[20] = res[1][0]; state[21] = res[1][1];   // out[10]
    state[22] = res[1][1] - res[0][1];              // dis0
    state[23] = 0.0f;                               // dis_sum
    state[24] = 0.0f;                               // dis_num
  }
}

__global__ __launch_bounds__(NB) void k_band(const float* __restrict__ heat, float* ws,
                                             float* __restrict__ out, int i) {
  int* counters = (int*)ws;
  float* state = ws + 16;
  float4* partials = (float4*)(ws + 48);

  // Band + state update (computed redundantly & deterministically by all threads)
  float y1 = state[2 * (i + 1) + 1];
  float y2 = state[2 * (i + 2) + 1];
  float dis = state[22], dsum = state[23], dnum = state[24];
  float last_y = floorf(y1);
  float tmp = ceilf(y2 - y1);
  bool cond = fabsf(tmp - dis) > 0.35f * dis;
  if (cond) { dsum += tmp; dnum += 1.0f; dis = dsum / fmaxf(dnum, 1.0f); }
  float start_raw = last_y - 1.8f * dis;
  float end_f = rintf(start_raw + 1.8f * dis);   // jnp.round = rint (half-to-even)
  float start_f = rintf(start_raw);
  int s = (int)fmaxf(start_f, 0.0f);
  int e = (int)fminf(end_f, (float)(HH - 1));
  bool band_valid = (s <= e) && (end_f >= 0.0f) && (start_f <= (float)(HH - 1));

  const int r = blockIdx.x;
  bool inband = band_valid && (r >= s) && (r <= e);
  if (inband) {
    const float* rowp = heat + ((size_t)i * HH + r) * WW;
    Tup t = row_reduce(rowp);
    if (threadIdx.x == 0) partials[r] = make_float4(t.m, t.z, t.sx, 0.0f);
  }
  __shared__ int s_last;
  if (threadIdx.x == 0) {
    __threadfence();
    int old = atomicAdd(&counters[1 + i], 1);
    s_last = (old == HH - 1) ? 1 : 0;
  }
  __syncthreads();
  if (!s_last) return;
  __threadfence();

  Tup acc = {-INFINITY, 0.0f, 0.0f, 0.0f};
  if (band_valid) {
    for (int rr = s + (int)threadIdx.x; rr <= e; rr += NB) {
      float4 p = partials[rr];
      Tup q = {p.x, p.y, p.z, p.y * (float)rr};
      comb(acc, q);
    }
  }
  acc = block_reduce4(acc);
  if (threadIdx.x == 0) {
    float M = acc.m, Z = acc.z, SX = acc.sx, SY = acc.sy;
    int ninr = band_valid ? (e - s + 1) : 0;
    int noutr = HH - ninr;
    if (noutr > 0) {
      // out-of-band elements are exactly 0 after masking; include analytically
      float M2 = fmaxf(M, 0.0f);
      float wi = (M == M2) ? 1.0f : expf(M - M2);   // M=-inf -> 0
      float wo = (M2 == 0.0f) ? 1.0f : expf(-M2);   // underflows to 0 for typical M
      Z *= wi; SX *= wi; SY *= wi;
      float nout_e = (float)noutr * (float)WW;                       // exact
      float sox = (float)noutr * 2096128.0f;                         // noutr * W(W-1)/2, exact
      float sinr = band_valid ? (float)(((long)(s + e) * (e - s + 1)) / 2) : 0.0f;  // exact
      float soy = (2096128.0f - sinr) * 2048.0f;                     // exact
      Z  += wo * nout_e;
      SX += wo * sox;
      SY += wo * soy;
    }
    float ax = SX / Z, ay = SY / Z;
    state[2 * i] = ax; state[2 * i + 1] = ay;
    state[22] = dis; state[23] = dsum; state[24] = dnum;
    if (i == 0) {
      for (int k = 0; k < 22; ++k) out[k] = state[k];
    }
  }
}

extern "C" void kernel_launch(void* const* d_in, const int* in_sizes, int n_in,
                              void* d_out, int out_size, void* d_ws, size_t ws_size,
                              hipStream_t stream) {
  const float* heat = (const float*)d_in[0];
  float* out = (float*)d_out;
  float* ws = (float*)d_ws;
  // zero the phase counters (ws is re-poisoned to 0xAA before every launch)
  hipMemsetAsync(d_ws, 0, 64, stream);
  hipLaunchKernelGGL(k_full, dim3(2 * HH), dim3(NB), 0, stream, heat, ws);
  for (int i = 8; i >= 0; --i) {
    hipLaunchKernelGGL(k_band, dim3(HH), dim3(NB), 0, stream, heat, ws, out, i);
  }
}

// Round 2
// 244.594 us; speedup vs baseline: 2.8269x; 2.8269x over previous
//
#include <hip/hip_runtime.h>
#include <math.h>

#define HH 2048
#define WW 2048
#define NB 256

// softmax-expectation accumulator: running max, sum(e), sum(e*x), sum(e*y)
struct Tup { float m, z, sx, sy; };

__device__ __forceinline__ void comb(Tup& a, const Tup& b) {
  float Mn = fmaxf(a.m, b.m);
  // (m==Mn)?1:expf guard avoids (-inf)-(-inf) = NaN when merging identities
  float w1 = (a.m == Mn) ? 1.0f : expf(a.m - Mn);
  float w2 = (b.m == Mn) ? 1.0f : expf(b.m - Mn);
  a.z  = a.z  * w1 + b.z  * w2;
  a.sx = a.sx * w1 + b.sx * w2;
  a.sy = a.sy * w1 + b.sy * w2;
  a.m  = Mn;
}

// Online-softmax reduce of one row (WW cols). All threads get the result.
// Leading __syncthreads protects shared arrays across repeated calls.
__device__ Tup row_reduce(const float* __restrict__ rowp) {
  const int tid = threadIdx.x;
  const float4* r4 = (const float4*)rowp;
  float m = -INFINITY, z = 0.0f, sx = 0.0f;
#pragma unroll
  for (int p = 0; p < WW / (4 * NB); ++p) {
    int i4 = tid + NB * p;
    float4 v = r4[i4];
    float vv[4] = {v.x, v.y, v.z, v.w};
    float c0 = (float)(i4 * 4);
#pragma unroll
    for (int k = 0; k < 4; ++k) {
      float x = vv[k] * 100.0f;   // BETA, matches reference f32 multiply
      if (x > m) {
        float sc = expf(m - x);   // first iter: expf(-inf) = 0
        z  = z  * sc + 1.0f;
        sx = sx * sc + (c0 + (float)k);
        m = x;
      } else {
        float w = expf(x - m);
        z  += w;
        sx += w * (c0 + (float)k);
      }
    }
  }
  __shared__ float sm_[NB], sz_[NB], ss_[NB];
  __syncthreads();              // WAR guard for repeated calls
  sm_[tid] = m; sz_[tid] = z; ss_[tid] = sx;
  __syncthreads();
  for (int off = NB / 2; off > 0; off >>= 1) {
    if (tid < off) {
      Tup a = {sm_[tid], sz_[tid], ss_[tid], 0.0f};
      Tup b = {sm_[tid + off], sz_[tid + off], ss_[tid + off], 0.0f};
      comb(a, b);
      sm_[tid] = a.m; sz_[tid] = a.z; ss_[tid] = a.sx;
    }
    __syncthreads();
  }
  Tup t = {sm_[0], sz_[0], ss_[0], 0.0f};
  return t;
}

__device__ Tup block_reduce4(Tup t) {
  __shared__ float am[NB], az[NB], axx[NB], ayy[NB];
  const int tid = threadIdx.x;
  __syncthreads();
  am[tid] = t.m; az[tid] = t.z; axx[tid] = t.sx; ayy[tid] = t.sy;
  __syncthreads();
  for (int off = NB / 2; off > 0; off >>= 1) {
    if (tid < off) {
      Tup a = {am[tid], az[tid], axx[tid], ayy[tid]};
      Tup b = {am[tid + off], az[tid + off], axx[tid + off], ayy[tid + off]};
      comb(a, b);
      am[tid] = a.m; az[tid] = a.z; axx[tid] = a.sx; ayy[tid] = a.sy;
    }
    __syncthreads();
  }
  Tup r = {am[0], az[0], axx[0], ayy[0]};
  return r;
}

// Merge per-row partials arr[r] for r in [s,e]; sy weight = r. All threads get result.
__device__ Tup merge_rows(const float4* arr, int s, int e) {
  Tup acc = {-INFINITY, 0.0f, 0.0f, 0.0f};
  for (int r = s + (int)threadIdx.x; r <= e; r += NB) {
    float4 p = arr[r];
    Tup q = {p.x, p.y, p.z, p.y * (float)r};
    comb(acc, q);
  }
  return block_reduce4(acc);
}

// Add analytic out-of-band complement (masked elements are exactly 0) and divide.
__device__ void finalize(Tup acc, int s, int e, bool valid, float& ax, float& ay) {
  float M = acc.m, Z = acc.z, SX = acc.sx, SY = acc.sy;
  int nin = valid ? (e - s + 1) : 0;
  int nout = HH - nin;
  if (nout > 0) {
    float M2 = fmaxf(M, 0.0f);
    float wi = (M == M2) ? 1.0f : expf(M - M2);   // M=-inf -> 0
    float wo = (M2 == 0.0f) ? 1.0f : expf(-M2);   // underflows to 0 for typical M
    Z *= wi; SX *= wi; SY *= wi;
    float nout_e = (float)nout * (float)WW;                                 // exact
    float sox = (float)nout * 2096128.0f;                                   // nout*W(W-1)/2
    float sinr = valid ? (float)(((long)(s + e) * (e - s + 1)) / 2) : 0.0f; // exact
    float soy = (2096128.0f - sinr) * 2048.0f;                              // exact
    Z  += wo * nout_e;
    SX += wo * sox;
    SY += wo * soy;
  }
  ax = SX / Z; ay = SY / Z;
}

// ws float layout: [0..21] out(11x2), [22] dis, [23] dsum, [24] dnum,
//                  [25] band_s, [26] band_e, [27] band_valid   (32-float header)
// F  = full partials, 4096 x float4  (ch9 rows at [0..2047], ch10 at [2048..4095])
// B0/B1 = band partial ping-pong buffers, 2048 x float4 each, indexed by abs row.

__global__ __launch_bounds__(NB) void k_rows(const float* __restrict__ heat, float* ws) {
  float4* F = (float4*)(ws + 32);
  const int b = blockIdx.x;
  const int ch = 9 + (b >> 11);
  const int r = b & (HH - 1);
  Tup t = row_reduce(heat + ((size_t)ch * HH + r) * WW);
  if (threadIdx.x == 0) F[b] = make_float4(t.m, t.z, t.sx, 0.0f);
}

__global__ __launch_bounds__(NB) void k_step(const float* __restrict__ heat, float* ws,
                                             float* __restrict__ out, int i) {
  float* state = ws;
  float4* F  = (float4*)(ws + 32);
  float4* B0 = F + 4096;
  float4* B1 = B0 + HH;

  float st[28];
  if (i == 8) {
    for (int k = 0; k < 28; ++k) st[k] = 0.0f;
    Tup a9  = merge_rows(F, 0, HH - 1);
    Tup a10 = merge_rows(F + HH, 0, HH - 1);
    float ax, ay;
    finalize(a9,  0, HH - 1, true, ax, ay); st[18] = ax; st[19] = ay;  // out[9]
    finalize(a10, 0, HH - 1, true, ax, ay); st[20] = ax; st[21] = ay;  // out[10]
    st[22] = st[21] - st[19];  // dis0
    st[23] = 0.0f; st[24] = 0.0f;
  } else {
    for (int k = 0; k < 28; ++k) st[k] = state[k];  // visible: prior kernel wrote it
    const int j = i + 1;                            // channel whose partials we merge
    const float4* Bprev = (j & 1) ? B1 : B0;
    int s = (int)st[25], e = (int)st[26];
    bool valid = (st[27] != 0.0f);
    Tup acc = {-INFINITY, 0.0f, 0.0f, 0.0f};
    if (valid) acc = merge_rows(Bprev, s, e);       // 'valid' is block-uniform
    float ax, ay;
    finalize(acc, s, e, valid, ax, ay);
    st[2 * j] = ax; st[2 * j + 1] = ay;
  }

  if (i >= 0) {
    // Band + dis-state update for channel i (all threads compute identically)
    float y1 = st[2 * (i + 1) + 1];
    float y2 = st[2 * (i + 2) + 1];
    float dis = st[22], dsum = st[23], dnum = st[24];
    float last_y = floorf(y1);
    float tmp = ceilf(y2 - y1);
    bool cond = fabsf(tmp - dis) > 0.35f * dis;
    if (cond) { dsum += tmp; dnum += 1.0f; dis = dsum / fmaxf(dnum, 1.0f); }
    float start_raw = last_y - 1.8f * dis;
    float end_f   = rintf(start_raw + 1.8f * dis);  // jnp.round = rint (half-to-even)
    float start_f = rintf(start_raw);
    int s2 = (int)fmaxf(start_f, 0.0f);
    int e2 = (int)fminf(end_f, (float)(HH - 1));
    bool bvalid = (s2 <= e2) && (end_f >= 0.0f) && (start_f <= (float)(HH - 1));
    st[22] = dis; st[23] = dsum; st[24] = dnum;
    st[25] = (float)s2; st[26] = (float)e2; st[27] = bvalid ? 1.0f : 0.0f;

    float4* Bcur = (i & 1) ? B1 : B0;
    if (bvalid) {
      for (int r = s2 + (int)blockIdx.x; r <= e2; r += (int)gridDim.x) {
        Tup t = row_reduce(heat + ((size_t)i * HH + r) * WW);
        if (threadIdx.x == 0) Bcur[r] = make_float4(t.m, t.z, t.sx, 0.0f);
      }
    }
    if (blockIdx.x == 0 && threadIdx.x == 0)
      for (int k = 0; k < 28; ++k) state[k] = st[k];
  } else {
    if (blockIdx.x == 0 && threadIdx.x == 0)
      for (int k = 0; k < 22; ++k) out[k] = st[k];
  }
}

extern "C" void kernel_launch(void* const* d_in, const int* in_sizes, int n_in,
                              void* d_out, int out_size, void* d_ws, size_t ws_size,
                              hipStream_t stream) {
  const float* heat = (const float*)d_in[0];
  float* out = (float*)d_out;
  float* ws = (float*)d_ws;
  hipLaunchKernelGGL(k_rows, dim3(2 * HH), dim3(NB), 0, stream, heat, ws);
  for (int i = 8; i >= 0; --i) {
    hipLaunchKernelGGL(k_step, dim3(NB), dim3(NB), 0, stream, heat, ws, out, i);
  }
  hipLaunchKernelGGL(k_step, dim3(1), dim3(NB), 0, stream, heat, ws, out, -1);
}